// Round 5
// baseline (333.468 us; speedup 1.0000x reference)
//
#include <hip/hip_runtime.h>

#define D_MODEL 1024
#define NTOK    4096
#define SEQ     2048
#define NH      16
#define HD      64

typedef __bf16 bh8  __attribute__((ext_vector_type(8)));
typedef __bf16 bf4  __attribute__((ext_vector_type(4)));
typedef float  f32x4 __attribute__((ext_vector_type(4)));
typedef int    i32x4 __attribute__((ext_vector_type(4)));

__device__ __forceinline__ unsigned short f2bf(float f) {       // RNE float->bf16
  unsigned int u = __float_as_uint(f);
  u += 0x7fffu + ((u >> 16) & 1u);
  return (unsigned short)(u >> 16);
}
__device__ __forceinline__ float bf2f(unsigned short h) {
  return __uint_as_float(((unsigned int)h) << 16);
}
__device__ __forceinline__ float exp2a(float x) {               // raw v_exp_f32 (2^x)
  float r; asm("v_exp_f32 %0, %1" : "=v"(r) : "v"(x)); return r;
}
// async global->LDS, 16B per lane; LDS dest wave-uniform (HW adds lane*16)
__device__ __forceinline__ void gl16(const void* g, void* l) {
  __builtin_amdgcn_global_load_lds((const __attribute__((address_space(1))) unsigned int*)g,
                                   (__attribute__((address_space(3))) unsigned int*)l, 16, 0, 0);
}

// ---------------------------------------------------------------------------
// Pack int32-held int8 -> int8, pre-swizzled for GEMM LDS tiles:
// within each 64-col group, 16B chunk c stored at c ^ ((m>>1)&3).
// ---------------------------------------------------------------------------
__device__ __forceinline__ void pack_row(const int* src, unsigned* dst, int m, int t) {
  int4 w = *(const int4*)(src + (size_t)m * 1024 + t * 4);
  unsigned p01 = __builtin_amdgcn_perm((unsigned)w.y, (unsigned)w.x, 0x00000400u);
  unsigned p23 = __builtin_amdgcn_perm((unsigned)w.w, (unsigned)w.z, 0x00000400u);
  unsigned r   = __builtin_amdgcn_perm(p23, p01, 0x05040100u);   // [x0,y0,z0,w0]
  int kg = t >> 4, c = (t >> 2) & 3, b4 = t & 3, sw = (m >> 1) & 3;
  dst[(size_t)m * 256 + kg * 16 + ((c ^ sw) << 2) + b4] = r;
}
__launch_bounds__(256)
__global__ void pack_x_k(const int* __restrict__ src, unsigned* __restrict__ dst) {
  pack_row(src, dst, blockIdx.x, threadIdx.x);
}
__launch_bounds__(256)
__global__ void pack_w_k(const int* __restrict__ s0, const int* __restrict__ s1,
                         const int* __restrict__ s2, const int* __restrict__ s3,
                         unsigned* __restrict__ d0, unsigned* __restrict__ d1,
                         unsigned* __restrict__ d2, unsigned* __restrict__ d3) {
  int wsel = blockIdx.x >> 10, m = blockIdx.x & 1023;
  const int* src = wsel == 0 ? s0 : wsel == 1 ? s1 : wsel == 2 ? s2 : s3;
  unsigned*  dst = wsel == 0 ? d0 : wsel == 1 ? d1 : wsel == 2 ? d2 : d3;
  pack_row(src, dst, m, threadIdx.x);
}

// ---------------------------------------------------------------------------
// Fused QKV int8 GEMM, 128x64 tiles (1536 blocks, ~6/CU), 4 waves x 32x64 out.
// z=0: q = x.wq^T, epi *SC -> hi/lo bf16 [b,h,s,d]
// z=1: k = x.wk^T          -> hi/lo bf16 [b,h,s,d]  (plain, no swizzle)
// z=2: v^T = wv.x^T        -> bf16 [b,h,d,s]
// ---------------------------------------------------------------------------
__launch_bounds__(256, 2)
__global__ void gemmQKV_k(const signed char* __restrict__ xp,
                          const signed char* __restrict__ wqp,
                          const signed char* __restrict__ wkp,
                          const signed char* __restrict__ wvp,
                          const float* __restrict__ xs,
                          const float* __restrict__ wqs, const float* __restrict__ bq,
                          const float* __restrict__ wks, const float* __restrict__ bk,
                          const float* __restrict__ wvs, const float* __restrict__ bv,
                          float SC,
                          unsigned short* __restrict__ qhi, unsigned short* __restrict__ qlo,
                          unsigned short* __restrict__ khi, unsigned short* __restrict__ klo,
                          unsigned short* __restrict__ vtw)
{
  __shared__ __align__(16) signed char As[2][8192];
  __shared__ __align__(16) signed char Bs[2][4096];
  const int id = blockIdx.x, z = id >> 9, rb = id & 511;
  const int t = threadIdx.x, wid = t >> 6, lane = t & 63, g = lane >> 4, li = lane & 15;
  const signed char *Ap, *Bp;
  int m0, n0;
  if (z == 2) { Ap = wvp; Bp = xp; m0 = (rb >> 6) * 128; n0 = (rb & 63) * 64; }
  else        { Ap = xp; Bp = z ? wkp : wqp; m0 = (rb >> 4) * 128; n0 = (rb & 15) * 64; }

  i32x4 acc[2][4];
#pragma unroll
  for (int i = 0; i < 2; ++i)
#pragma unroll
    for (int j = 0; j < 4; ++j) acc[i][j] = (i32x4){0, 0, 0, 0};

#pragma unroll
  for (int i = 0; i < 2; ++i) {
    int unit = (wid * 2 + i) * 64 + lane, r = unit >> 2, c = unit & 3;
    gl16(Ap + (size_t)(m0 + r) * 1024 + c * 16, (char*)As[0] + (wid * 2 + i) * 1024);
  }
  { int unit = wid * 64 + lane, r = unit >> 2, c = unit & 3;
    gl16(Bp + (size_t)(n0 + r) * 1024 + c * 16, (char*)Bs[0] + wid * 1024); }
  __syncthreads();
  int p = 0;
#pragma unroll 1
  for (int ks = 0; ks < 16; ++ks) {
    if (ks < 15) {
      const int k0 = (ks + 1) * 64;
#pragma unroll
      for (int i = 0; i < 2; ++i) {
        int unit = (wid * 2 + i) * 64 + lane, r = unit >> 2, c = unit & 3;
        gl16(Ap + (size_t)(m0 + r) * 1024 + k0 + c * 16, (char*)As[p ^ 1] + (wid * 2 + i) * 1024);
      }
      { int unit = wid * 64 + lane, r = unit >> 2, c = unit & 3;
        gl16(Bp + (size_t)(n0 + r) * 1024 + k0 + c * 16, (char*)Bs[p ^ 1] + wid * 1024); }
    }
    i32x4 af[2], bfr[4];
#pragma unroll
    for (int mt = 0; mt < 2; ++mt) {
      int row = wid * 32 + mt * 16 + li;
      af[mt] = *(const i32x4*)(As[p] + row * 64 + ((g ^ ((row >> 1) & 3)) << 4));
    }
#pragma unroll
    for (int nt = 0; nt < 4; ++nt) {
      int row = nt * 16 + li;
      bfr[nt] = *(const i32x4*)(Bs[p] + row * 64 + ((g ^ ((row >> 1) & 3)) << 4));
    }
    __builtin_amdgcn_s_setprio(1);
#pragma unroll
    for (int mt = 0; mt < 2; ++mt)
#pragma unroll
      for (int nt = 0; nt < 4; ++nt)
        acc[mt][nt] = __builtin_amdgcn_mfma_i32_16x16x64_i8(af[mt], bfr[nt], acc[mt][nt], 0, 0, 0);
    __builtin_amdgcn_s_setprio(0);
    __syncthreads();
    p ^= 1;
  }

  // epilogue: D layout col=lane&15 (=n), row=(lane>>4)*4+r (=m)
#pragma unroll
  for (int mt = 0; mt < 2; ++mt) {
#pragma unroll
    for (int nt = 0; nt < 4; ++nt) {
      const int nn = n0 + nt * 16 + li;
#pragma unroll
      for (int r = 0; r < 4; ++r) {
        const int m = m0 + wid * 32 + mt * 16 + g * 4 + r;
        const float a = (float)acc[mt][nt][r];          // exact: |acc| < 2^24
        if (z == 2) {
          float f = a * (wvs[m] * xs[nn]) + bv[m];
          int hh = m >> 6, d = m & 63, bb = nn >> 11, s = nn & 2047;
          vtw[(((size_t)(bb * NH + hh)) * HD + d) * SEQ + s] = f2bf(f);
        } else {
          const float* wsc = z ? wks : wqs;
          const float* wbi = z ? bk : bq;
          float f = (a * (xs[m] * wsc[nn]) + wbi[nn]) * (z ? 1.0f : SC);
          int bb = m >> 11, s = m & 2047, hh = nn >> 6, d = nn & 63;
          size_t o = (((size_t)(bb * NH + hh)) * SEQ + s) * HD + d;
          unsigned short hi = f2bf(f);
          unsigned short lo = f2bf(f - bf2f(hi));
          if (z) { khi[o] = hi; klo[o] = lo; }
          else   { qhi[o] = hi; qlo[o] = lo; }
        }
      }
    }
  }
}

// ---------------------------------------------------------------------------
// Out-proj int8 GEMM, 128x64 tiles (512 blocks). C = o_q . wo^T -> fp32.
// ---------------------------------------------------------------------------
__launch_bounds__(256, 2)
__global__ void gemmO_k(const signed char* __restrict__ Ap, const signed char* __restrict__ Bp,
                        const float* __restrict__ sA, const float* __restrict__ sB,
                        const float* __restrict__ bias, float* __restrict__ outF)
{
  __shared__ __align__(16) signed char As[2][8192];
  __shared__ __align__(16) signed char Bs[2][4096];
  const int id = blockIdx.x;
  const int m0 = (id >> 4) * 128, n0 = (id & 15) * 64;
  const int t = threadIdx.x, wid = t >> 6, lane = t & 63, g = lane >> 4, li = lane & 15;

  i32x4 acc[2][4];
#pragma unroll
  for (int i = 0; i < 2; ++i)
#pragma unroll
    for (int j = 0; j < 4; ++j) acc[i][j] = (i32x4){0, 0, 0, 0};

#pragma unroll
  for (int i = 0; i < 2; ++i) {
    int unit = (wid * 2 + i) * 64 + lane, r = unit >> 2, c = unit & 3;
    gl16(Ap + (size_t)(m0 + r) * 1024 + c * 16, (char*)As[0] + (wid * 2 + i) * 1024);
  }
  { int unit = wid * 64 + lane, r = unit >> 2, c = unit & 3;
    gl16(Bp + (size_t)(n0 + r) * 1024 + c * 16, (char*)Bs[0] + wid * 1024); }
  __syncthreads();
  int p = 0;
#pragma unroll 1
  for (int ks = 0; ks < 16; ++ks) {
    if (ks < 15) {
      const int k0 = (ks + 1) * 64;
#pragma unroll
      for (int i = 0; i < 2; ++i) {
        int unit = (wid * 2 + i) * 64 + lane, r = unit >> 2, c = unit & 3;
        gl16(Ap + (size_t)(m0 + r) * 1024 + k0 + c * 16, (char*)As[p ^ 1] + (wid * 2 + i) * 1024);
      }
      { int unit = wid * 64 + lane, r = unit >> 2, c = unit & 3;
        gl16(Bp + (size_t)(n0 + r) * 1024 + k0 + c * 16, (char*)Bs[p ^ 1] + wid * 1024); }
    }
    i32x4 af[2], bfr[4];
#pragma unroll
    for (int mt = 0; mt < 2; ++mt) {
      int row = wid * 32 + mt * 16 + li;
      af[mt] = *(const i32x4*)(As[p] + row * 64 + ((g ^ ((row >> 1) & 3)) << 4));
    }
#pragma unroll
    for (int nt = 0; nt < 4; ++nt) {
      int row = nt * 16 + li;
      bfr[nt] = *(const i32x4*)(Bs[p] + row * 64 + ((g ^ ((row >> 1) & 3)) << 4));
    }
    __builtin_amdgcn_s_setprio(1);
#pragma unroll
    for (int mt = 0; mt < 2; ++mt)
#pragma unroll
      for (int nt = 0; nt < 4; ++nt)
        acc[mt][nt] = __builtin_amdgcn_mfma_i32_16x16x64_i8(af[mt], bfr[nt], acc[mt][nt], 0, 0, 0);
    __builtin_amdgcn_s_setprio(0);
    __syncthreads();
    p ^= 1;
  }

#pragma unroll
  for (int mt = 0; mt < 2; ++mt)
#pragma unroll
    for (int nt = 0; nt < 4; ++nt) {
      const int nn = n0 + nt * 16 + li;
#pragma unroll
      for (int r = 0; r < 4; ++r) {
        const int m = m0 + wid * 32 + mt * 16 + g * 4 + r;
        outF[(size_t)m * 1024 + nn] = (float)acc[mt][nt][r] * (sA[m] * sB[nn]) + bias[nn];
      }
    }
}

// ---------------------------------------------------------------------------
// Flash attention, BARRIER-FREE: each wave independent, 32 q-rows (2x16 sets).
// K hi/lo and V loaded directly global->reg (L1/L2-served, 64B segments).
// S^T = K.Q^T; exp2-domain softmax (q pre-scaled); O^T = V^T.P^T.
// LDS only for per-wave P transpose (no __syncthreads anywhere).
// ---------------------------------------------------------------------------
__launch_bounds__(256, 2)
__global__ void attn_k(const unsigned short* __restrict__ qhi, const unsigned short* __restrict__ qlo,
                       const unsigned short* __restrict__ khi, const unsigned short* __restrict__ klo,
                       const unsigned short* __restrict__ vt, float* __restrict__ attn)
{
  __shared__ __align__(16) unsigned short ps[4][2][1024];
  const int t = threadIdx.x;
  const int w = t >> 6, lane = t & 63, g = lane >> 4, li = lane & 15;
  const int q0 = blockIdx.x * 128, h = blockIdx.y, b = blockIdx.z;
  const int bh = b * NH + h;
  const int qA = q0 + w * 32 + li, qB = qA + 16;

  bh8 qhf[2][2], qlf[2][2];                        // [set][kc]
#pragma unroll
  for (int kc = 0; kc < 2; ++kc) {
    qhf[0][kc] = *(const bh8*)(qhi + ((size_t)bh * SEQ + qA) * HD + kc * 32 + g * 8);
    qlf[0][kc] = *(const bh8*)(qlo + ((size_t)bh * SEQ + qA) * HD + kc * 32 + g * 8);
    qhf[1][kc] = *(const bh8*)(qhi + ((size_t)bh * SEQ + qB) * HD + kc * 32 + g * 8);
    qlf[1][kc] = *(const bh8*)(qlo + ((size_t)bh * SEQ + qB) * HD + kc * 32 + g * 8);
  }
  const unsigned short* kb = khi + (size_t)bh * SEQ * HD;
  const unsigned short* lb = klo + (size_t)bh * SEQ * HD;
  const unsigned short* vb = vt  + (size_t)bh * HD * SEQ;

  float m_run[2] = {-INFINITY, -INFINITY}, l_run[2] = {0.0f, 0.0f};
  f32x4 ot[2][4];
#pragma unroll
  for (int s = 0; s < 2; ++s)
#pragma unroll
    for (int i = 0; i < 4; ++i) ot[s][i] = (f32x4)0.0f;

#pragma unroll 1
  for (int it = 0; it < 32; ++it) {
    const int kk0 = it * 64;
    // K fragments direct global->reg: 16 rows x 64B segments per load
    bh8 kh[4][2], kl[4][2];
#pragma unroll
    for (int kt2 = 0; kt2 < 4; ++kt2)
#pragma unroll
      for (int kc = 0; kc < 2; ++kc) {
        kh[kt2][kc] = *(const bh8*)(kb + (size_t)(kk0 + kt2 * 16 + li) * HD + kc * 32 + g * 8);
        kl[kt2][kc] = *(const bh8*)(lb + (size_t)(kk0 + kt2 * 16 + li) * HD + kc * 32 + g * 8);
      }
    // QK^T for both q-sets
    f32x4 sa[2][4];
#pragma unroll
    for (int s = 0; s < 2; ++s)
#pragma unroll
      for (int i = 0; i < 4; ++i) sa[s][i] = (f32x4)0.0f;
#pragma unroll
    for (int kt2 = 0; kt2 < 4; ++kt2) {
#pragma unroll
      for (int kc = 0; kc < 2; ++kc) {
        __builtin_amdgcn_s_setprio(1);
        sa[0][kt2] = __builtin_amdgcn_mfma_f32_16x16x32_bf16(kh[kt2][kc], qhf[0][kc], sa[0][kt2], 0, 0, 0);
        sa[1][kt2] = __builtin_amdgcn_mfma_f32_16x16x32_bf16(kh[kt2][kc], qhf[1][kc], sa[1][kt2], 0, 0, 0);
        sa[0][kt2] = __builtin_amdgcn_mfma_f32_16x16x32_bf16(kh[kt2][kc], qlf[0][kc], sa[0][kt2], 0, 0, 0);
        sa[1][kt2] = __builtin_amdgcn_mfma_f32_16x16x32_bf16(kh[kt2][kc], qlf[1][kc], sa[1][kt2], 0, 0, 0);
        sa[0][kt2] = __builtin_amdgcn_mfma_f32_16x16x32_bf16(kl[kt2][kc], qhf[0][kc], sa[0][kt2], 0, 0, 0);
        sa[1][kt2] = __builtin_amdgcn_mfma_f32_16x16x32_bf16(kl[kt2][kc], qhf[1][kc], sa[1][kt2], 0, 0, 0);
        __builtin_amdgcn_s_setprio(0);
      }
    }
    // V fragments (issued early; consumed after softmax -> latency covered)
    bh8 vv[2][4];
#pragma unroll
    for (int kc2 = 0; kc2 < 2; ++kc2)
#pragma unroll
      for (int dt = 0; dt < 4; ++dt)
        vv[kc2][dt] = *(const bh8*)(vb + (size_t)(dt * 16 + li) * SEQ + kk0 + kc2 * 32 + g * 8);
    // online softmax (exp2 domain), per set
#pragma unroll
    for (int s = 0; s < 2; ++s) {
      float sm = -INFINITY;
#pragma unroll
      for (int kt2 = 0; kt2 < 4; ++kt2)
#pragma unroll
        for (int r = 0; r < 4; ++r) sm = fmaxf(sm, sa[s][kt2][r]);
      sm = fmaxf(sm, __shfl_xor(sm, 16));
      sm = fmaxf(sm, __shfl_xor(sm, 32));
      if (__any(sm > m_run[s] + 11.0f)) {            // defer-max: P bounded by 2^11
        float mn = fmaxf(m_run[s], sm);
        float alpha = exp2a(m_run[s] - mn);
        l_run[s] *= alpha;
#pragma unroll
        for (int i = 0; i < 4; ++i) ot[s][i] *= alpha;
        m_run[s] = mn;
      }
      float ts = 0.0f;
#pragma unroll
      for (int kt2 = 0; kt2 < 4; ++kt2)
#pragma unroll
        for (int r = 0; r < 4; ++r) {
          float e = exp2a(sa[s][kt2][r] - m_run[s]);
          sa[s][kt2][r] = e; ts += e;
        }
      ts += __shfl_xor(ts, 16);
      ts += __shfl_xor(ts, 32);
      l_run[s] += ts;
      // P^T -> per-wave LDS: kk = kt2*16 + g*4 + r at row q=li
#pragma unroll
      for (int kt2 = 0; kt2 < 4; ++kt2) {
        bf4 pk = { (__bf16)sa[s][kt2][0], (__bf16)sa[s][kt2][1],
                   (__bf16)sa[s][kt2][2], (__bf16)sa[s][kt2][3] };
        int lchunk = (kt2 << 1) | (g >> 1);
        *(bf4*)((char*)ps[w][s] + li * 128 + ((lchunk ^ (li & 7)) << 4) + ((g & 1) << 3)) = pk;
      }
    }
    asm volatile("s_waitcnt lgkmcnt(0)" ::: "memory");
    __builtin_amdgcn_sched_barrier(0);
    bh8 pf[2][2];
#pragma unroll
    for (int s = 0; s < 2; ++s)
#pragma unroll
      for (int kc2 = 0; kc2 < 2; ++kc2)
        pf[s][kc2] = *(const bh8*)((const char*)ps[w][s] + li * 128 + ((((kc2 << 2) | g) ^ (li & 7)) << 4));
#pragma unroll
    for (int kc2 = 0; kc2 < 2; ++kc2) {
      __builtin_amdgcn_s_setprio(1);
#pragma unroll
      for (int dt = 0; dt < 4; ++dt) {
        ot[0][dt] = __builtin_amdgcn_mfma_f32_16x16x32_bf16(vv[kc2][dt], pf[0][kc2], ot[0][dt], 0, 0, 0);
        ot[1][dt] = __builtin_amdgcn_mfma_f32_16x16x32_bf16(vv[kc2][dt], pf[1][kc2], ot[1][dt], 0, 0, 0);
      }
      __builtin_amdgcn_s_setprio(0);
    }
  }

#pragma unroll
  for (int s = 0; s < 2; ++s) {
    const float inv = 1.0f / l_run[s];
    const int n = b * SEQ + (s ? qB : qA);
#pragma unroll
    for (int dt = 0; dt < 4; ++dt) {
      float4 o4;
      o4.x = ot[s][dt][0] * inv; o4.y = ot[s][dt][1] * inv;
      o4.z = ot[s][dt][2] * inv; o4.w = ot[s][dt][3] * inv;
      *(float4*)(attn + (size_t)n * D_MODEL + h * HD + dt * 16 + g * 4) = o4;
    }
  }
}

// ---------------------------------------------------------------------------
// Per-token dynamic int8 quantization; writes packed pre-swizzled int8 rows.
// ---------------------------------------------------------------------------
__launch_bounds__(256)
__global__ void quant_k(const float* __restrict__ attn, unsigned* __restrict__ oqp,
                        float* __restrict__ osc)
{
  const int row = blockIdx.x, t = threadIdx.x;
  float4 v = *(const float4*)(attn + (size_t)row * D_MODEL + t * 4);
  float mx = fmaxf(fmaxf(fabsf(v.x), fabsf(v.y)), fmaxf(fabsf(v.z), fabsf(v.w)));
#pragma unroll
  for (int off = 1; off < 64; off <<= 1) mx = fmaxf(mx, __shfl_xor(mx, off));
  __shared__ float red[4];
  if ((t & 63) == 0) red[t >> 6] = mx;
  __syncthreads();
  mx = fmaxf(fmaxf(red[0], red[1]), fmaxf(red[2], red[3]));
  const float s = mx / 127.0f;
  if (t == 0) osc[row] = s;
  int q0 = (int)fminf(fmaxf(rintf(v.x / s), -127.f), 127.f);
  int q1 = (int)fminf(fmaxf(rintf(v.y / s), -127.f), 127.f);
  int q2 = (int)fminf(fmaxf(rintf(v.z / s), -127.f), 127.f);
  int q3 = (int)fminf(fmaxf(rintf(v.w / s), -127.f), 127.f);
  unsigned pk = ((unsigned)q0 & 255u) | (((unsigned)q1 & 255u) << 8) |
                (((unsigned)q2 & 255u) << 16) | (((unsigned)q3 & 255u) << 24);
  int kg = t >> 4, c = (t >> 2) & 3, b4 = t & 3, sw = (row >> 1) & 3;
  oqp[(size_t)row * 256 + kg * 16 + ((c ^ sw) << 2) + b4] = pk;
}

// ---------------------------------------------------------------------------
extern "C" void kernel_launch(void* const* d_in, const int* in_sizes, int n_in,
                              void* d_out, int out_size, void* d_ws, size_t ws_size,
                              hipStream_t stream)
{
  const int*   x   = (const int*)d_in[0];
  const float* xs  = (const float*)d_in[1];
  const int*   wq  = (const int*)d_in[2];
  const float* wqs = (const float*)d_in[3];
  const float* bq  = (const float*)d_in[4];
  const int*   wk  = (const int*)d_in[5];
  const float* wks = (const float*)d_in[6];
  const float* bk  = (const float*)d_in[7];
  const int*   wv  = (const int*)d_in[8];
  const float* wvs = (const float*)d_in[9];
  const float* bv  = (const float*)d_in[10];
  const int*   wo  = (const int*)d_in[11];
  const float* wos = (const float*)d_in[12];
  const float* bo  = (const float*)d_in[13];
  float* out = (float*)d_out;

  char* ws = (char*)d_ws;
  const size_t MB = 1024 * 1024;
  unsigned* xp  = (unsigned*)(ws);                 // 4 MB packed x
  unsigned* wqp = (unsigned*)(ws + 4 * MB);        // 1 MB each packed weights
  unsigned* wkp = (unsigned*)(ws + 5 * MB);
  unsigned* wvp = (unsigned*)(ws + 6 * MB);
  unsigned* wop = (unsigned*)(ws + 7 * MB);
  unsigned short* qhi = (unsigned short*)(ws + 8 * MB);    // 8 MB each
  unsigned short* qlo = (unsigned short*)(ws + 16 * MB);
  unsigned short* khi = (unsigned short*)(ws + 24 * MB);
  unsigned short* klo = (unsigned short*)(ws + 32 * MB);
  unsigned short* vtw = (unsigned short*)(ws + 40 * MB);
  float*          att = (float*)(ws + 48 * MB);            // 16 MB
  unsigned*       oqp = (unsigned*)(ws);                   // overlay on xp (dead)
  float*          osc = (float*)(ws + 4 * MB);             // overlay on wqp (dead)

  const float SC = 0.125f * 1.44269504088896340736f;       // (1/sqrt(hd)) * log2(e)
  dim3 blk(256);
  pack_x_k<<<dim3(4096), blk, 0, stream>>>(x, xp);
  pack_w_k<<<dim3(4096), blk, 0, stream>>>(wq, wk, wv, wo, wqp, wkp, wvp, wop);
  gemmQKV_k<<<dim3(1536), blk, 0, stream>>>((const signed char*)xp, (const signed char*)wqp,
                                            (const signed char*)wkp, (const signed char*)wvp,
                                            xs, wqs, bq, wks, bk, wvs, bv, SC,
                                            qhi, qlo, khi, klo, vtw);
  attn_k<<<dim3(16, NH, 2), blk, 0, stream>>>(qhi, qlo, khi, klo, vtw, att);
  quant_k<<<dim3(4096), blk, 0, stream>>>(att, oqp, osc);
  gemmO_k<<<dim3(512), blk, 0, stream>>>((const signed char*)oqp, (const signed char*)wop,
                                         osc, wos, bo, out);
}

// Round 6
// 244.423 us; speedup vs baseline: 1.3643x; 1.3643x over previous
//
#include <hip/hip_runtime.h>

#define D_MODEL 1024
#define NTOK    4096
#define SEQ     2048
#define NH      16
#define HD      64

typedef __bf16 bh8  __attribute__((ext_vector_type(8)));
typedef __bf16 bf4  __attribute__((ext_vector_type(4)));
typedef float  f32x4 __attribute__((ext_vector_type(4)));
typedef int    i32x4 __attribute__((ext_vector_type(4)));

__device__ __forceinline__ unsigned short f2bf(float f) {       // RNE float->bf16
  unsigned int u = __float_as_uint(f);
  u += 0x7fffu + ((u >> 16) & 1u);
  return (unsigned short)(u >> 16);
}
__device__ __forceinline__ float exp2a(float x) {               // raw v_exp_f32 (2^x)
  float r; asm("v_exp_f32 %0, %1" : "=v"(r) : "v"(x)); return r;
}
// async global->LDS, 16B per lane; LDS dest wave-uniform (HW adds lane*16)
__device__ __forceinline__ void gl16(const void* g, void* l) {
  __builtin_amdgcn_global_load_lds((const __attribute__((address_space(1))) unsigned int*)g,
                                   (__attribute__((address_space(3))) unsigned int*)l, 16, 0, 0);
}

// ---------------------------------------------------------------------------
// Pack int32-held int8 -> int8, pre-swizzled for GEMM LDS tiles:
// within each 64-col group, 16B chunk c stored at c ^ ((m>>1)&3).
// grid 8192: [0,4096) = x rows, [4096,8192) = weight rows (4 x 1024).
// ---------------------------------------------------------------------------
__device__ __forceinline__ void pack_row(const int* src, unsigned* dst, int m, int t) {
  int4 w = *(const int4*)(src + (size_t)m * 1024 + t * 4);
  unsigned p01 = __builtin_amdgcn_perm((unsigned)w.y, (unsigned)w.x, 0x00000400u);
  unsigned p23 = __builtin_amdgcn_perm((unsigned)w.w, (unsigned)w.z, 0x00000400u);
  unsigned r   = __builtin_amdgcn_perm(p23, p01, 0x05040100u);   // [x0,y0,z0,w0]
  int kg = t >> 4, c = (t >> 2) & 3, b4 = t & 3, sw = (m >> 1) & 3;
  dst[(size_t)m * 256 + kg * 16 + ((c ^ sw) << 2) + b4] = r;
}
__launch_bounds__(256)
__global__ void pack_k(const int* __restrict__ x,
                       const int* __restrict__ s0, const int* __restrict__ s1,
                       const int* __restrict__ s2, const int* __restrict__ s3,
                       unsigned* __restrict__ dx,
                       unsigned* __restrict__ d0, unsigned* __restrict__ d1,
                       unsigned* __restrict__ d2, unsigned* __restrict__ d3) {
  int bid = blockIdx.x;
  if (bid < 4096) { pack_row(x, dx, bid, threadIdx.x); return; }
  bid -= 4096;
  int wsel = bid >> 10, m = bid & 1023;
  const int* src = wsel == 0 ? s0 : wsel == 1 ? s1 : wsel == 2 ? s2 : s3;
  unsigned*  dst = wsel == 0 ? d0 : wsel == 1 ? d1 : wsel == 2 ? d2 : d3;
  pack_row(src, dst, m, threadIdx.x);
}

// ---------------------------------------------------------------------------
// Fused QKV int8 GEMM, 128x64 tiles (1536 blocks), 4 waves x 32x64 out.
// z=0: q = x.wq^T, *SC  -> 15-bit int8 hi/lo [b,h,s,d] + sq scale
// z=1: k = x.wk^T       -> 15-bit int8 hi/lo [b,h,s,d] chunk-swizzled + sk scale
// z=2: v^T = wv.x^T     -> bf16 [b,h,d,s] with attn V-LDS swizzle
// ---------------------------------------------------------------------------
__launch_bounds__(256, 2)
__global__ void gemmQKV_k(const signed char* __restrict__ xp,
                          const signed char* __restrict__ wqp,
                          const signed char* __restrict__ wkp,
                          const signed char* __restrict__ wvp,
                          const float* __restrict__ xs,
                          const float* __restrict__ wqs, const float* __restrict__ bq,
                          const float* __restrict__ wks, const float* __restrict__ bk,
                          const float* __restrict__ wvs, const float* __restrict__ bv,
                          float SC,
                          signed char* __restrict__ qp8h, signed char* __restrict__ qp8l,
                          signed char* __restrict__ kp8h, signed char* __restrict__ kp8l,
                          float* __restrict__ sq, float* __restrict__ sk,
                          unsigned short* __restrict__ vtw)
{
  __shared__ __align__(16) signed char As[2][8192];
  __shared__ __align__(16) signed char Bs[2][4096];
  const int id = blockIdx.x, z = id >> 9, rb = id & 511;
  const int t = threadIdx.x, wid = t >> 6, lane = t & 63, g = lane >> 4, li = lane & 15;
  const signed char *Ap, *Bp;
  int m0, n0;
  if (z == 2) { Ap = wvp; Bp = xp; m0 = (rb >> 6) * 128; n0 = (rb & 63) * 64; }
  else        { Ap = xp; Bp = z ? wkp : wqp; m0 = (rb >> 4) * 128; n0 = (rb & 15) * 64; }

  i32x4 acc[2][4];
#pragma unroll
  for (int i = 0; i < 2; ++i)
#pragma unroll
    for (int j = 0; j < 4; ++j) acc[i][j] = (i32x4){0, 0, 0, 0};

#pragma unroll
  for (int i = 0; i < 2; ++i) {
    int unit = (wid * 2 + i) * 64 + lane, r = unit >> 2, c = unit & 3;
    gl16(Ap + (size_t)(m0 + r) * 1024 + c * 16, (char*)As[0] + (wid * 2 + i) * 1024);
  }
  { int unit = wid * 64 + lane, r = unit >> 2, c = unit & 3;
    gl16(Bp + (size_t)(n0 + r) * 1024 + c * 16, (char*)Bs[0] + wid * 1024); }
  __syncthreads();
  int p = 0;
#pragma unroll 1
  for (int ks = 0; ks < 16; ++ks) {
    if (ks < 15) {
      const int k0 = (ks + 1) * 64;
#pragma unroll
      for (int i = 0; i < 2; ++i) {
        int unit = (wid * 2 + i) * 64 + lane, r = unit >> 2, c = unit & 3;
        gl16(Ap + (size_t)(m0 + r) * 1024 + k0 + c * 16, (char*)As[p ^ 1] + (wid * 2 + i) * 1024);
      }
      { int unit = wid * 64 + lane, r = unit >> 2, c = unit & 3;
        gl16(Bp + (size_t)(n0 + r) * 1024 + k0 + c * 16, (char*)Bs[p ^ 1] + wid * 1024); }
    }
    i32x4 af[2], bfr[4];
#pragma unroll
    for (int mt = 0; mt < 2; ++mt) {
      int row = wid * 32 + mt * 16 + li;
      af[mt] = *(const i32x4*)(As[p] + row * 64 + ((g ^ ((row >> 1) & 3)) << 4));
    }
#pragma unroll
    for (int nt = 0; nt < 4; ++nt) {
      int row = nt * 16 + li;
      bfr[nt] = *(const i32x4*)(Bs[p] + row * 64 + ((g ^ ((row >> 1) & 3)) << 4));
    }
    __builtin_amdgcn_s_setprio(1);
#pragma unroll
    for (int mt = 0; mt < 2; ++mt)
#pragma unroll
      for (int nt = 0; nt < 4; ++nt)
        acc[mt][nt] = __builtin_amdgcn_mfma_i32_16x16x64_i8(af[mt], bfr[nt], acc[mt][nt], 0, 0, 0);
    __builtin_amdgcn_s_setprio(0);
    __syncthreads();
    p ^= 1;
  }

  // epilogue: D layout col=lane&15 (=n), row=(lane>>4)*4+r (=m)
  if (z == 2) {
#pragma unroll
    for (int mt = 0; mt < 2; ++mt)
#pragma unroll
      for (int nt = 0; nt < 4; ++nt) {
        const int nn = n0 + nt * 16 + li;
#pragma unroll
        for (int r = 0; r < 4; ++r) {
          const int m = m0 + wid * 32 + mt * 16 + g * 4 + r;
          float f = (float)acc[mt][nt][r] * (wvs[m] * xs[nn]) + bv[m];
          int hh = m >> 6, d = m & 63, bb = nn >> 11, s = nn & 2047;
          int ss = (s & ~63) | (((((s >> 3) & 7) ^ (d & 7)) << 3) | (s & 7));
          vtw[(((size_t)(bb * NH + hh)) * HD + d) * SEQ + ss] = f2bf(f);
        }
      }
  } else {
    const float* wsc = z ? wks : wqs;
    const float* wbi = z ? bk : bq;
    signed char* dh = z ? kp8h : qp8h;
    signed char* dl = z ? kp8l : qp8l;
    float*       sc = z ? sk : sq;
    const int head = (n0 >> 6) & 15;
    float ws4[4], wb4[4];
#pragma unroll
    for (int nt = 0; nt < 4; ++nt) { ws4[nt] = wsc[n0 + nt * 16 + li]; wb4[nt] = wbi[n0 + nt * 16 + li]; }
#pragma unroll
    for (int mt = 0; mt < 2; ++mt) {
      float4 xs4 = *(const float4*)(xs + m0 + wid * 32 + mt * 16 + g * 4);
      float xa[4] = {xs4.x, xs4.y, xs4.z, xs4.w};
#pragma unroll
      for (int r = 0; r < 4; ++r) {
        const int m = m0 + wid * 32 + mt * 16 + g * 4 + r;
        float f[4];
#pragma unroll
        for (int nt = 0; nt < 4; ++nt) {
          f[nt] = fmaf((float)acc[mt][nt][r], xa[r] * ws4[nt], wb4[nt]);
          if (z == 0) f[nt] *= SC;
        }
        float mx = fmaxf(fmaxf(fabsf(f[0]), fabsf(f[1])), fmaxf(fabsf(f[2]), fabsf(f[3])));
        mx = fmaxf(mx, __shfl_xor(mx, 1));
        mx = fmaxf(mx, __shfl_xor(mx, 2));
        mx = fmaxf(mx, __shfl_xor(mx, 4));
        mx = fmaxf(mx, __shfl_xor(mx, 8));
        mx = fmaxf(mx, 1e-20f);
        const float inv = 32512.0f / mx;
        const int bb = m >> 11, sR = m & 2047;
        const size_t rowo = ((size_t)(bb * NH + head) * SEQ + sR) * 64;
#pragma unroll
        for (int nt = 0; nt < 4; ++nt) {
          int qi = (int)rintf(f[nt] * inv);
          int qh = (qi + 128) >> 8;
          int ql = qi - (qh << 8);
          int d = nt * 16 + li;
          int dd = z ? ((((d >> 4) ^ (m & 3)) << 4) | (d & 15)) : d;
          dh[rowo + dd] = (signed char)qh;
          dl[rowo + dd] = (signed char)ql;
        }
        if (li == 0) sc[(size_t)(bb * NH + head) * SEQ + sR] = mx * (1.0f / 32512.0f);
      }
    }
  }
}

// ---------------------------------------------------------------------------
// Out-proj int8 GEMM, 128x64 tiles (512 blocks). C = o_q . wo^T -> fp32.
// ---------------------------------------------------------------------------
__launch_bounds__(256, 2)
__global__ void gemmO_k(const signed char* __restrict__ Ap, const signed char* __restrict__ Bp,
                        const float* __restrict__ sA, const float* __restrict__ sB,
                        const float* __restrict__ bias, float* __restrict__ outF)
{
  __shared__ __align__(16) signed char As[2][8192];
  __shared__ __align__(16) signed char Bs[2][4096];
  const int id = blockIdx.x;
  const int m0 = (id >> 4) * 128, n0 = (id & 15) * 64;
  const int t = threadIdx.x, wid = t >> 6, lane = t & 63, g = lane >> 4, li = lane & 15;

  i32x4 acc[2][4];
#pragma unroll
  for (int i = 0; i < 2; ++i)
#pragma unroll
    for (int j = 0; j < 4; ++j) acc[i][j] = (i32x4){0, 0, 0, 0};

#pragma unroll
  for (int i = 0; i < 2; ++i) {
    int unit = (wid * 2 + i) * 64 + lane, r = unit >> 2, c = unit & 3;
    gl16(Ap + (size_t)(m0 + r) * 1024 + c * 16, (char*)As[0] + (wid * 2 + i) * 1024);
  }
  { int unit = wid * 64 + lane, r = unit >> 2, c = unit & 3;
    gl16(Bp + (size_t)(n0 + r) * 1024 + c * 16, (char*)Bs[0] + wid * 1024); }
  __syncthreads();
  int p = 0;
#pragma unroll 1
  for (int ks = 0; ks < 16; ++ks) {
    if (ks < 15) {
      const int k0 = (ks + 1) * 64;
#pragma unroll
      for (int i = 0; i < 2; ++i) {
        int unit = (wid * 2 + i) * 64 + lane, r = unit >> 2, c = unit & 3;
        gl16(Ap + (size_t)(m0 + r) * 1024 + k0 + c * 16, (char*)As[p ^ 1] + (wid * 2 + i) * 1024);
      }
      { int unit = wid * 64 + lane, r = unit >> 2, c = unit & 3;
        gl16(Bp + (size_t)(n0 + r) * 1024 + k0 + c * 16, (char*)Bs[p ^ 1] + wid * 1024); }
    }
    i32x4 af[2], bfr[4];
#pragma unroll
    for (int mt = 0; mt < 2; ++mt) {
      int row = wid * 32 + mt * 16 + li;
      af[mt] = *(const i32x4*)(As[p] + row * 64 + ((g ^ ((row >> 1) & 3)) << 4));
    }
#pragma unroll
    for (int nt = 0; nt < 4; ++nt) {
      int row = nt * 16 + li;
      bfr[nt] = *(const i32x4*)(Bs[p] + row * 64 + ((g ^ ((row >> 1) & 3)) << 4));
    }
    __builtin_amdgcn_s_setprio(1);
#pragma unroll
    for (int mt = 0; mt < 2; ++mt)
#pragma unroll
      for (int nt = 0; nt < 4; ++nt)
        acc[mt][nt] = __builtin_amdgcn_mfma_i32_16x16x64_i8(af[mt], bfr[nt], acc[mt][nt], 0, 0, 0);
    __builtin_amdgcn_s_setprio(0);
    __syncthreads();
    p ^= 1;
  }

#pragma unroll
  for (int mt = 0; mt < 2; ++mt)
#pragma unroll
    for (int nt = 0; nt < 4; ++nt) {
      const int nn = n0 + nt * 16 + li;
#pragma unroll
      for (int r = 0; r < 4; ++r) {
        const int m = m0 + wid * 32 + mt * 16 + g * 4 + r;
        outF[(size_t)m * 1024 + nn] = (float)acc[mt][nt][r] * (sA[m] * sB[nn]) + bias[nn];
      }
    }
}

// ---------------------------------------------------------------------------
// Flash attention with int8 QK^T (15-bit exact split): S^T = K.Q^T via 4
// mfma_i32_16x16x64_i8 per 16x16 score tile; score = sq*sk*(65536*hh+256*mid+ll).
// K(h,l) int8 + V bf16 staged via coalesced gl16, double-buffered, 1 barrier/it.
// 4 waves x 32 q (2 sets). exp2-domain softmax (SC folded in q), defer-max.
// O^T = V^T.P^T via ps-transpose (validated layout).
// ---------------------------------------------------------------------------
__launch_bounds__(256, 2)
__global__ void attn_k(const signed char* __restrict__ qp8h, const signed char* __restrict__ qp8l,
                       const signed char* __restrict__ kp8h, const signed char* __restrict__ kp8l,
                       const float* __restrict__ sq, const float* __restrict__ sk,
                       const unsigned short* __restrict__ vt, float* __restrict__ attn)
{
  __shared__ __align__(16) signed char kbh[2][4096], kbl[2][4096];
  __shared__ __align__(16) unsigned short vts[2][4096];
  __shared__ __align__(16) unsigned short ps[4][2][1024];
  const int t = threadIdx.x;
  const int w = t >> 6, lane = t & 63, g = lane >> 4, li = lane & 15;
  const int q0 = blockIdx.x * 128, h = blockIdx.y, b = blockIdx.z;
  const int bh = b * NH + h;
  const int qA = q0 + w * 32 + li, qB = qA + 16;

  // Q fragments: 16B of int8 (k = g*16..+15) per set, hi and lo
  i32x4 qh8[2], ql8[2];
  qh8[0] = *(const i32x4*)(qp8h + ((size_t)bh * SEQ + qA) * 64 + g * 16);
  ql8[0] = *(const i32x4*)(qp8l + ((size_t)bh * SEQ + qA) * 64 + g * 16);
  qh8[1] = *(const i32x4*)(qp8h + ((size_t)bh * SEQ + qB) * 64 + g * 16);
  ql8[1] = *(const i32x4*)(qp8l + ((size_t)bh * SEQ + qB) * 64 + g * 16);
  const float sqv[2] = { sq[(size_t)bh * SEQ + qA], sq[(size_t)bh * SEQ + qB] };
  const signed char* kbg = kp8h + (size_t)bh * SEQ * 64;
  const signed char* klg = kp8l + (size_t)bh * SEQ * 64;
  const float* skg = sk + (size_t)bh * SEQ;
  const unsigned short* vb = vt + (size_t)bh * HD * SEQ;

  float m_run[2] = {-INFINITY, -INFINITY}, l_run[2] = {0.0f, 0.0f};
  f32x4 ot[2][4];
#pragma unroll
  for (int s = 0; s < 2; ++s)
#pragma unroll
    for (int i = 0; i < 4; ++i) ot[s][i] = (f32x4)0.0f;

  // prologue: stage tile 0 into buf 0 (coalesced; K 4KB+4KB, V 8KB)
  {
    int u = w * 64 + lane, r = u >> 2, c = u & 3;
    gl16(kbg + r * 64 + c * 16, (char*)kbh[0] + w * 1024);
    gl16(klg + r * 64 + c * 16, (char*)kbl[0] + w * 1024);
#pragma unroll
    for (int i = 0; i < 2; ++i) {
      int u2 = (w * 2 + i) * 64 + lane, rv = u2 >> 3, cv = u2 & 7;
      gl16(vb + (size_t)rv * SEQ + cv * 8, (char*)vts[0] + (w * 2 + i) * 1024);
    }
  }

#pragma unroll 1
  for (int it = 0; it < 32; ++it) {
    const int kk0 = it * 64, cur = it & 1;
    __syncthreads();                      // buf[cur] staged; prev reads done
    // K fragments from LDS (8 x ds_read_b128, conflict-balanced)
    i32x4 kh[4], kl[4];
#pragma unroll
    for (int kt2 = 0; kt2 < 4; ++kt2) {
      int row = kt2 * 16 + li, co = (g ^ (row & 3)) << 4;
      kh[kt2] = *(const i32x4*)(kbh[cur] + row * 64 + co);
      kl[kt2] = *(const i32x4*)(kbl[cur] + row * 64 + co);
    }
    // stage next tile
    if (it < 31) {
      int u = w * 64 + lane, r = u >> 2, c = u & 3;
      gl16(kbg + (size_t)(kk0 + 64 + r) * 64 + c * 16, (char*)kbh[cur ^ 1] + w * 1024);
      gl16(klg + (size_t)(kk0 + 64 + r) * 64 + c * 16, (char*)kbl[cur ^ 1] + w * 1024);
#pragma unroll
      for (int i = 0; i < 2; ++i) {
        int u2 = (w * 2 + i) * 64 + lane, rv = u2 >> 3, cv = u2 & 7;
        gl16(vb + (size_t)rv * SEQ + kk0 + 64 + cv * 8, (char*)vts[cur ^ 1] + (w * 2 + i) * 1024);
      }
    }
    // QK^T: per kt2 per set, 4 int8 MFMAs (hh, mid x2, ll) -> float scores
    f32x4 sa[2][4];
#pragma unroll
    for (int kt2 = 0; kt2 < 4; ++kt2) {
      float4 sk4 = *(const float4*)(skg + kk0 + kt2 * 16 + g * 4);
      float ska[4] = {sk4.x, sk4.y, sk4.z, sk4.w};
#pragma unroll
      for (int s = 0; s < 2; ++s) {
        i32x4 z4 = (i32x4){0, 0, 0, 0};
        __builtin_amdgcn_s_setprio(1);
        i32x4 hh = __builtin_amdgcn_mfma_i32_16x16x64_i8(kh[kt2], qh8[s], z4, 0, 0, 0);
        i32x4 mm = __builtin_amdgcn_mfma_i32_16x16x64_i8(kl[kt2], qh8[s], z4, 0, 0, 0);
        mm = __builtin_amdgcn_mfma_i32_16x16x64_i8(kh[kt2], ql8[s], mm, 0, 0, 0);
        i32x4 ll = __builtin_amdgcn_mfma_i32_16x16x64_i8(kl[kt2], ql8[s], z4, 0, 0, 0);
        __builtin_amdgcn_s_setprio(0);
#pragma unroll
        for (int r = 0; r < 4; ++r) {
          int A = (hh[r] << 8) + mm[r];                        // exact int32
          sa[s][kt2][r] = fmaf((float)A, 256.0f, (float)ll[r]) * (sqv[s] * ska[r]);
        }
      }
    }
    // online softmax (exp2 domain), per set
#pragma unroll
    for (int s = 0; s < 2; ++s) {
      float sm = -INFINITY;
#pragma unroll
      for (int kt2 = 0; kt2 < 4; ++kt2)
#pragma unroll
        for (int r = 0; r < 4; ++r) sm = fmaxf(sm, sa[s][kt2][r]);
      sm = fmaxf(sm, __shfl_xor(sm, 16));
      sm = fmaxf(sm, __shfl_xor(sm, 32));
      if (__any(sm > m_run[s] + 11.0f)) {            // defer-max: P bounded by 2^11
        float mn = fmaxf(m_run[s], sm);
        float alpha = exp2a(m_run[s] - mn);
        l_run[s] *= alpha;
#pragma unroll
        for (int i = 0; i < 4; ++i) ot[s][i] *= alpha;
        m_run[s] = mn;
      }
      float ts = 0.0f;
#pragma unroll
      for (int kt2 = 0; kt2 < 4; ++kt2)
#pragma unroll
        for (int r = 0; r < 4; ++r) {
          float e = exp2a(sa[s][kt2][r] - m_run[s]);
          sa[s][kt2][r] = e; ts += e;
        }
      ts += __shfl_xor(ts, 16);
      ts += __shfl_xor(ts, 32);
      l_run[s] += ts;
      // P^T -> per-wave LDS: kk = kt2*16 + g*4 + r at row q=li
#pragma unroll
      for (int kt2 = 0; kt2 < 4; ++kt2) {
        bf4 pk = { (__bf16)sa[s][kt2][0], (__bf16)sa[s][kt2][1],
                   (__bf16)sa[s][kt2][2], (__bf16)sa[s][kt2][3] };
        int lchunk = (kt2 << 1) | (g >> 1);
        *(bf4*)((char*)ps[w][s] + li * 128 + ((lchunk ^ (li & 7)) << 4) + ((g & 1) << 3)) = pk;
      }
    }
    asm volatile("s_waitcnt lgkmcnt(0)" ::: "memory");
    __builtin_amdgcn_sched_barrier(0);
    // PV: O^T += V^T . P^T
    bh8 pf[2][2];
#pragma unroll
    for (int s = 0; s < 2; ++s)
#pragma unroll
      for (int kc2 = 0; kc2 < 2; ++kc2)
        pf[s][kc2] = *(const bh8*)((const char*)ps[w][s] + li * 128 + ((((kc2 << 2) | g) ^ (li & 7)) << 4));
#pragma unroll
    for (int kc2 = 0; kc2 < 2; ++kc2) {
      __builtin_amdgcn_s_setprio(1);
#pragma unroll
      for (int dt = 0; dt < 4; ++dt) {
        int rowd = dt * 16 + li;
        bh8 vf = *(const bh8*)((const char*)vts[cur] + rowd * 128 + ((((kc2 << 2) | g) ^ (rowd & 7)) << 4));
        ot[0][dt] = __builtin_amdgcn_mfma_f32_16x16x32_bf16(vf, pf[0][kc2], ot[0][dt], 0, 0, 0);
        ot[1][dt] = __builtin_amdgcn_mfma_f32_16x16x32_bf16(vf, pf[1][kc2], ot[1][dt], 0, 0, 0);
      }
      __builtin_amdgcn_s_setprio(0);
    }
  }

#pragma unroll
  for (int s = 0; s < 2; ++s) {
    const float inv = 1.0f / l_run[s];
    const int n = b * SEQ + (s ? qB : qA);
#pragma unroll
    for (int dt = 0; dt < 4; ++dt) {
      float4 o4;
      o4.x = ot[s][dt][0] * inv; o4.y = ot[s][dt][1] * inv;
      o4.z = ot[s][dt][2] * inv; o4.w = ot[s][dt][3] * inv;
      *(float4*)(attn + (size_t)n * D_MODEL + h * HD + dt * 16 + g * 4) = o4;
    }
  }
}

// ---------------------------------------------------------------------------
// Per-token dynamic int8 quantization; writes packed pre-swizzled int8 rows.
// ---------------------------------------------------------------------------
__launch_bounds__(256)
__global__ void quant_k(const float* __restrict__ attn, unsigned* __restrict__ oqp,
                        float* __restrict__ osc)
{
  const int row = blockIdx.x, t = threadIdx.x;
  float4 v = *(const float4*)(attn + (size_t)row * D_MODEL + t * 4);
  float mx = fmaxf(fmaxf(fabsf(v.x), fabsf(v.y)), fmaxf(fabsf(v.z), fabsf(v.w)));
#pragma unroll
  for (int off = 1; off < 64; off <<= 1) mx = fmaxf(mx, __shfl_xor(mx, off));
  __shared__ float red[4];
  if ((t & 63) == 0) red[t >> 6] = mx;
  __syncthreads();
  mx = fmaxf(fmaxf(red[0], red[1]), fmaxf(red[2], red[3]));
  const float s = mx / 127.0f;
  if (t == 0) osc[row] = s;
  int q0 = (int)fminf(fmaxf(rintf(v.x / s), -127.f), 127.f);
  int q1 = (int)fminf(fmaxf(rintf(v.y / s), -127.f), 127.f);
  int q2 = (int)fminf(fmaxf(rintf(v.z / s), -127.f), 127.f);
  int q3 = (int)fminf(fmaxf(rintf(v.w / s), -127.f), 127.f);
  unsigned pk = ((unsigned)q0 & 255u) | (((unsigned)q1 & 255u) << 8) |
                (((unsigned)q2 & 255u) << 16) | (((unsigned)q3 & 255u) << 24);
  int kg = t >> 4, c = (t >> 2) & 3, b4 = t & 3, sw = (row >> 1) & 3;
  oqp[(size_t)row * 256 + kg * 16 + ((c ^ sw) << 2) + b4] = pk;
}

// ---------------------------------------------------------------------------
extern "C" void kernel_launch(void* const* d_in, const int* in_sizes, int n_in,
                              void* d_out, int out_size, void* d_ws, size_t ws_size,
                              hipStream_t stream)
{
  const int*   x   = (const int*)d_in[0];
  const float* xs  = (const float*)d_in[1];
  const int*   wq  = (const int*)d_in[2];
  const float* wqs = (const float*)d_in[3];
  const float* bq  = (const float*)d_in[4];
  const int*   wk  = (const int*)d_in[5];
  const float* wks = (const float*)d_in[6];
  const float* bk  = (const float*)d_in[7];
  const int*   wv  = (const int*)d_in[8];
  const float* wvs = (const float*)d_in[9];
  const float* bv  = (const float*)d_in[10];
  const int*   wo  = (const int*)d_in[11];
  const float* wos = (const float*)d_in[12];
  const float* bo  = (const float*)d_in[13];
  float* out = (float*)d_out;

  char* ws = (char*)d_ws;
  const size_t MB = 1024 * 1024;
  unsigned* xp  = (unsigned*)(ws);                     // 4 MB packed x
  unsigned* wqp = (unsigned*)(ws + 4 * MB);            // 1 MB each packed weights
  unsigned* wkp = (unsigned*)(ws + 5 * MB);
  unsigned* wvp = (unsigned*)(ws + 6 * MB);
  unsigned* wop = (unsigned*)(ws + 7 * MB);
  signed char* qp8h = (signed char*)(ws + 8 * MB);     // 4 MB each int8 q/k
  signed char* qp8l = (signed char*)(ws + 12 * MB);
  signed char* kp8h = (signed char*)(ws + 16 * MB);
  signed char* kp8l = (signed char*)(ws + 20 * MB);
  float*       sqs  = (float*)(ws + 24 * MB);          // 256 KB
  float*       sks  = (float*)(ws + 24 * MB + 256 * 1024);
  unsigned short* vtw = (unsigned short*)(ws + 25 * MB);  // 8 MB
  float*          att = (float*)(ws + 33 * MB);           // 16 MB
  unsigned*       oqp = (unsigned*)(ws);                  // overlay on xp (dead)
  float*          osc = (float*)(ws + 4 * MB);            // overlay on wqp (dead)

  const float SC = 0.125f * 1.44269504088896340736f;   // (1/sqrt(hd)) * log2(e)
  dim3 blk(256);
  pack_k<<<dim3(8192), blk, 0, stream>>>(x, wq, wk, wv, wo, xp, wqp, wkp, wvp, wop);
  gemmQKV_k<<<dim3(1536), blk, 0, stream>>>((const signed char*)xp, (const signed char*)wqp,
                                            (const signed char*)wkp, (const signed char*)wvp,
                                            xs, wqs, bq, wks, bk, wvs, bv, SC,
                                            qp8h, qp8l, kp8h, kp8l, sqs, sks, vtw);
  attn_k<<<dim3(16, NH, 2), blk, 0, stream>>>(qp8h, qp8l, kp8h, kp8l, sqs, sks, vtw, att);
  quant_k<<<dim3(4096), blk, 0, stream>>>(att, oqp, osc);
  gemmO_k<<<dim3(512), blk, 0, stream>>>((const signed char*)oqp, (const signed char*)wop,
                                         osc, wos, bo, out);
}

// Round 7
// 235.458 us; speedup vs baseline: 1.4163x; 1.0381x over previous
//
#include <hip/hip_runtime.h>

#define D_MODEL 1024
#define NTOK    4096
#define SEQ     2048
#define NH      16
#define HD      64

typedef __bf16 bh8  __attribute__((ext_vector_type(8)));
typedef __bf16 bf4  __attribute__((ext_vector_type(4)));
typedef float  f32x4 __attribute__((ext_vector_type(4)));
typedef int    i32x4 __attribute__((ext_vector_type(4)));

__device__ __forceinline__ unsigned short f2bf(float f) {       // RNE float->bf16
  unsigned int u = __float_as_uint(f);
  u += 0x7fffu + ((u >> 16) & 1u);
  return (unsigned short)(u >> 16);
}
__device__ __forceinline__ float exp2a(float x) {               // raw v_exp_f32 (2^x)
  float r; asm("v_exp_f32 %0, %1" : "=v"(r) : "v"(x)); return r;
}
// async global->LDS, 16B per lane; LDS dest wave-uniform (HW adds lane*16)
__device__ __forceinline__ void gl16(const void* g, void* l) {
  __builtin_amdgcn_global_load_lds((const __attribute__((address_space(1))) unsigned int*)g,
                                   (__attribute__((address_space(3))) unsigned int*)l, 16, 0, 0);
}

// ---------------------------------------------------------------------------
// Pack int32-held int8 -> int8, pre-swizzled for GEMM LDS tiles:
// within each 64-col group, 16B chunk c stored at c ^ ((m>>1)&3).
// grid 8192: [0,4096) = x rows, [4096,8192) = weight rows (4 x 1024).
// ---------------------------------------------------------------------------
__device__ __forceinline__ void pack_row(const int* src, unsigned* dst, int m, int t) {
  int4 w = *(const int4*)(src + (size_t)m * 1024 + t * 4);
  unsigned p01 = __builtin_amdgcn_perm((unsigned)w.y, (unsigned)w.x, 0x00000400u);
  unsigned p23 = __builtin_amdgcn_perm((unsigned)w.w, (unsigned)w.z, 0x00000400u);
  unsigned r   = __builtin_amdgcn_perm(p23, p01, 0x05040100u);   // [x0,y0,z0,w0]
  int kg = t >> 4, c = (t >> 2) & 3, b4 = t & 3, sw = (m >> 1) & 3;
  dst[(size_t)m * 256 + kg * 16 + ((c ^ sw) << 2) + b4] = r;
}
__launch_bounds__(256)
__global__ void pack_k(const int* __restrict__ x,
                       const int* __restrict__ s0, const int* __restrict__ s1,
                       const int* __restrict__ s2, const int* __restrict__ s3,
                       unsigned* __restrict__ dx,
                       unsigned* __restrict__ d0, unsigned* __restrict__ d1,
                       unsigned* __restrict__ d2, unsigned* __restrict__ d3) {
  int bid = blockIdx.x;
  if (bid < 4096) { pack_row(x, dx, bid, threadIdx.x); return; }
  bid -= 4096;
  int wsel = bid >> 10, m = bid & 1023;
  const int* src = wsel == 0 ? s0 : wsel == 1 ? s1 : wsel == 2 ? s2 : s3;
  unsigned*  dst = wsel == 0 ? d0 : wsel == 1 ? d1 : wsel == 2 ? d2 : d3;
  pack_row(src, dst, m, threadIdx.x);
}

// ---------------------------------------------------------------------------
// Fused QKV int8 GEMM, 128x64 tiles (1536 blocks), 4 waves x 32x64 out.
// z=0: q = x.wq^T, *SC  -> 15-bit int8 hi/lo [b,h,s,d] + sq scale
// z=1: k = x.wk^T       -> 15-bit int8 hi/lo [b,h,s,d] chunk-swizzled + sk scale
// z=2: v^T = wv.x^T     -> bf16 [b,h,d,s] with attn V-LDS swizzle
// ---------------------------------------------------------------------------
__launch_bounds__(256, 2)
__global__ void gemmQKV_k(const signed char* __restrict__ xp,
                          const signed char* __restrict__ wqp,
                          const signed char* __restrict__ wkp,
                          const signed char* __restrict__ wvp,
                          const float* __restrict__ xs,
                          const float* __restrict__ wqs, const float* __restrict__ bq,
                          const float* __restrict__ wks, const float* __restrict__ bk,
                          const float* __restrict__ wvs, const float* __restrict__ bv,
                          float SC,
                          signed char* __restrict__ qp8h, signed char* __restrict__ qp8l,
                          signed char* __restrict__ kp8h, signed char* __restrict__ kp8l,
                          float* __restrict__ sq, float* __restrict__ sk,
                          unsigned short* __restrict__ vtw)
{
  __shared__ __align__(16) signed char As[2][8192];
  __shared__ __align__(16) signed char Bs[2][4096];
  const int id = blockIdx.x, z = id >> 9, rb = id & 511;
  const int t = threadIdx.x, wid = t >> 6, lane = t & 63, g = lane >> 4, li = lane & 15;
  const signed char *Ap, *Bp;
  int m0, n0;
  if (z == 2) { Ap = wvp; Bp = xp; m0 = (rb >> 6) * 128; n0 = (rb & 63) * 64; }
  else        { Ap = xp; Bp = z ? wkp : wqp; m0 = (rb >> 4) * 128; n0 = (rb & 15) * 64; }

  i32x4 acc[2][4];
#pragma unroll
  for (int i = 0; i < 2; ++i)
#pragma unroll
    for (int j = 0; j < 4; ++j) acc[i][j] = (i32x4){0, 0, 0, 0};

#pragma unroll
  for (int i = 0; i < 2; ++i) {
    int unit = (wid * 2 + i) * 64 + lane, r = unit >> 2, c = unit & 3;
    gl16(Ap + (size_t)(m0 + r) * 1024 + c * 16, (char*)As[0] + (wid * 2 + i) * 1024);
  }
  { int unit = wid * 64 + lane, r = unit >> 2, c = unit & 3;
    gl16(Bp + (size_t)(n0 + r) * 1024 + c * 16, (char*)Bs[0] + wid * 1024); }
  __syncthreads();
  int p = 0;
#pragma unroll 1
  for (int ks = 0; ks < 16; ++ks) {
    if (ks < 15) {
      const int k0 = (ks + 1) * 64;
#pragma unroll
      for (int i = 0; i < 2; ++i) {
        int unit = (wid * 2 + i) * 64 + lane, r = unit >> 2, c = unit & 3;
        gl16(Ap + (size_t)(m0 + r) * 1024 + k0 + c * 16, (char*)As[p ^ 1] + (wid * 2 + i) * 1024);
      }
      { int unit = wid * 64 + lane, r = unit >> 2, c = unit & 3;
        gl16(Bp + (size_t)(n0 + r) * 1024 + k0 + c * 16, (char*)Bs[p ^ 1] + wid * 1024); }
    }
    i32x4 af[2], bfr[4];
#pragma unroll
    for (int mt = 0; mt < 2; ++mt) {
      int row = wid * 32 + mt * 16 + li;
      af[mt] = *(const i32x4*)(As[p] + row * 64 + ((g ^ ((row >> 1) & 3)) << 4));
    }
#pragma unroll
    for (int nt = 0; nt < 4; ++nt) {
      int row = nt * 16 + li;
      bfr[nt] = *(const i32x4*)(Bs[p] + row * 64 + ((g ^ ((row >> 1) & 3)) << 4));
    }
    __builtin_amdgcn_s_setprio(1);
#pragma unroll
    for (int mt = 0; mt < 2; ++mt)
#pragma unroll
      for (int nt = 0; nt < 4; ++nt)
        acc[mt][nt] = __builtin_amdgcn_mfma_i32_16x16x64_i8(af[mt], bfr[nt], acc[mt][nt], 0, 0, 0);
    __builtin_amdgcn_s_setprio(0);
    __syncthreads();
    p ^= 1;
  }

  // epilogue: D layout col=lane&15 (=n), row=(lane>>4)*4+r (=m)
  if (z == 2) {
#pragma unroll
    for (int mt = 0; mt < 2; ++mt)
#pragma unroll
      for (int nt = 0; nt < 4; ++nt) {
        const int nn = n0 + nt * 16 + li;
#pragma unroll
        for (int r = 0; r < 4; ++r) {
          const int m = m0 + wid * 32 + mt * 16 + g * 4 + r;
          float f = (float)acc[mt][nt][r] * (wvs[m] * xs[nn]) + bv[m];
          int hh = m >> 6, d = m & 63, bb = nn >> 11, s = nn & 2047;
          int ss = (s & ~63) | (((((s >> 3) & 7) ^ (d & 7)) << 3) | (s & 7));
          vtw[(((size_t)(bb * NH + hh)) * HD + d) * SEQ + ss] = f2bf(f);
        }
      }
  } else {
    const float* wsc = z ? wks : wqs;
    const float* wbi = z ? bk : bq;
    signed char* dh = z ? kp8h : qp8h;
    signed char* dl = z ? kp8l : qp8l;
    float*       sc = z ? sk : sq;
    const int head = (n0 >> 6) & 15;
    float ws4[4], wb4[4];
#pragma unroll
    for (int nt = 0; nt < 4; ++nt) { ws4[nt] = wsc[n0 + nt * 16 + li]; wb4[nt] = wbi[n0 + nt * 16 + li]; }
#pragma unroll
    for (int mt = 0; mt < 2; ++mt) {
      float4 xs4 = *(const float4*)(xs + m0 + wid * 32 + mt * 16 + g * 4);
      float xa[4] = {xs4.x, xs4.y, xs4.z, xs4.w};
#pragma unroll
      for (int r = 0; r < 4; ++r) {
        const int m = m0 + wid * 32 + mt * 16 + g * 4 + r;
        float f[4];
#pragma unroll
        for (int nt = 0; nt < 4; ++nt) {
          f[nt] = fmaf((float)acc[mt][nt][r], xa[r] * ws4[nt], wb4[nt]);
          if (z == 0) f[nt] *= SC;
        }
        float mx = fmaxf(fmaxf(fabsf(f[0]), fabsf(f[1])), fmaxf(fabsf(f[2]), fabsf(f[3])));
        mx = fmaxf(mx, __shfl_xor(mx, 1));
        mx = fmaxf(mx, __shfl_xor(mx, 2));
        mx = fmaxf(mx, __shfl_xor(mx, 4));
        mx = fmaxf(mx, __shfl_xor(mx, 8));
        mx = fmaxf(mx, 1e-20f);
        const float inv = 32512.0f / mx;
        const int bb = m >> 11, sR = m & 2047;
        const size_t rowo = ((size_t)(bb * NH + head) * SEQ + sR) * 64;
#pragma unroll
        for (int nt = 0; nt < 4; ++nt) {
          int qi = (int)rintf(f[nt] * inv);
          int qh = (qi + 128) >> 8;
          int ql = qi - (qh << 8);
          int d = nt * 16 + li;
          int dd = z ? ((((d >> 4) ^ ((m >> 1) & 3)) << 4) | (d & 15)) : d;
          dh[rowo + dd] = (signed char)qh;
          dl[rowo + dd] = (signed char)ql;
        }
        if (li == 0) sc[(size_t)(bb * NH + head) * SEQ + sR] = mx * (1.0f / 32512.0f);
      }
    }
  }
}

// ---------------------------------------------------------------------------
// Out-proj int8 GEMM, 128x64 tiles (512 blocks). C = o_q . wo^T -> fp32.
// ---------------------------------------------------------------------------
__launch_bounds__(256, 2)
__global__ void gemmO_k(const signed char* __restrict__ Ap, const signed char* __restrict__ Bp,
                        const float* __restrict__ sA, const float* __restrict__ sB,
                        const float* __restrict__ bias, float* __restrict__ outF)
{
  __shared__ __align__(16) signed char As[2][8192];
  __shared__ __align__(16) signed char Bs[2][4096];
  const int id = blockIdx.x;
  const int m0 = (id >> 4) * 128, n0 = (id & 15) * 64;
  const int t = threadIdx.x, wid = t >> 6, lane = t & 63, g = lane >> 4, li = lane & 15;

  i32x4 acc[2][4];
#pragma unroll
  for (int i = 0; i < 2; ++i)
#pragma unroll
    for (int j = 0; j < 4; ++j) acc[i][j] = (i32x4){0, 0, 0, 0};

#pragma unroll
  for (int i = 0; i < 2; ++i) {
    int unit = (wid * 2 + i) * 64 + lane, r = unit >> 2, c = unit & 3;
    gl16(Ap + (size_t)(m0 + r) * 1024 + c * 16, (char*)As[0] + (wid * 2 + i) * 1024);
  }
  { int unit = wid * 64 + lane, r = unit >> 2, c = unit & 3;
    gl16(Bp + (size_t)(n0 + r) * 1024 + c * 16, (char*)Bs[0] + wid * 1024); }
  __syncthreads();
  int p = 0;
#pragma unroll 1
  for (int ks = 0; ks < 16; ++ks) {
    if (ks < 15) {
      const int k0 = (ks + 1) * 64;
#pragma unroll
      for (int i = 0; i < 2; ++i) {
        int unit = (wid * 2 + i) * 64 + lane, r = unit >> 2, c = unit & 3;
        gl16(Ap + (size_t)(m0 + r) * 1024 + k0 + c * 16, (char*)As[p ^ 1] + (wid * 2 + i) * 1024);
      }
      { int unit = wid * 64 + lane, r = unit >> 2, c = unit & 3;
        gl16(Bp + (size_t)(n0 + r) * 1024 + k0 + c * 16, (char*)Bs[p ^ 1] + wid * 1024); }
    }
    i32x4 af[2], bfr[4];
#pragma unroll
    for (int mt = 0; mt < 2; ++mt) {
      int row = wid * 32 + mt * 16 + li;
      af[mt] = *(const i32x4*)(As[p] + row * 64 + ((g ^ ((row >> 1) & 3)) << 4));
    }
#pragma unroll
    for (int nt = 0; nt < 4; ++nt) {
      int row = nt * 16 + li;
      bfr[nt] = *(const i32x4*)(Bs[p] + row * 64 + ((g ^ ((row >> 1) & 3)) << 4));
    }
    __builtin_amdgcn_s_setprio(1);
#pragma unroll
    for (int mt = 0; mt < 2; ++mt)
#pragma unroll
      for (int nt = 0; nt < 4; ++nt)
        acc[mt][nt] = __builtin_amdgcn_mfma_i32_16x16x64_i8(af[mt], bfr[nt], acc[mt][nt], 0, 0, 0);
    __builtin_amdgcn_s_setprio(0);
    __syncthreads();
    p ^= 1;
  }

#pragma unroll
  for (int mt = 0; mt < 2; ++mt)
#pragma unroll
    for (int nt = 0; nt < 4; ++nt) {
      const int nn = n0 + nt * 16 + li;
#pragma unroll
      for (int r = 0; r < 4; ++r) {
        const int m = m0 + wid * 32 + mt * 16 + g * 4 + r;
        outF[(size_t)m * 1024 + nn] = (float)acc[mt][nt][r] * (sA[m] * sB[nn]) + bias[nn];
      }
    }
}

// ---------------------------------------------------------------------------
// Flash attention with int8 QK^T (15-bit split, ll term dropped: |err|<~0.05):
// S^T = K.Q^T via 3 mfma_i32_16x16x64_i8 per 16x16 tile; score=(256*hh+mid)*256*sq*sk.
// K(h,l) int8 + V bf16 staged via coalesced gl16, double-buffered, 1 barrier/it.
// K LDS chunk-swizzle: chunk ^ ((row>>1)&3)  [even rows alias mod 32 banks at
// 64B rows; (row>>1)&3 spreads them 2-way = free; (row&3) was 4-way].
// 4 waves x 32 q (2 sets). exp2-domain softmax (SC folded in q), defer-max.
// O^T = V^T.P^T via ps-transpose.
// ---------------------------------------------------------------------------
__launch_bounds__(256, 2)
__global__ void attn_k(const signed char* __restrict__ qp8h, const signed char* __restrict__ qp8l,
                       const signed char* __restrict__ kp8h, const signed char* __restrict__ kp8l,
                       const float* __restrict__ sq, const float* __restrict__ sk,
                       const unsigned short* __restrict__ vt, float* __restrict__ attn)
{
  __shared__ __align__(16) signed char kbh[2][4096], kbl[2][4096];
  __shared__ __align__(16) unsigned short vts[2][4096];
  __shared__ __align__(16) unsigned short ps[4][2][1024];
  const int t = threadIdx.x;
  const int w = t >> 6, lane = t & 63, g = lane >> 4, li = lane & 15;
  const int q0 = blockIdx.x * 128, h = blockIdx.y, b = blockIdx.z;
  const int bh = b * NH + h;
  const int qA = q0 + w * 32 + li, qB = qA + 16;

  // Q fragments: 16B of int8 (k = g*16..+15) per set, hi and lo
  i32x4 qh8[2], ql8[2];
  qh8[0] = *(const i32x4*)(qp8h + ((size_t)bh * SEQ + qA) * 64 + g * 16);
  ql8[0] = *(const i32x4*)(qp8l + ((size_t)bh * SEQ + qA) * 64 + g * 16);
  qh8[1] = *(const i32x4*)(qp8h + ((size_t)bh * SEQ + qB) * 64 + g * 16);
  ql8[1] = *(const i32x4*)(qp8l + ((size_t)bh * SEQ + qB) * 64 + g * 16);
  // fold the 256 of score=256*A into the q scale
  const float sq256[2] = { sq[(size_t)bh * SEQ + qA] * 256.0f,
                           sq[(size_t)bh * SEQ + qB] * 256.0f };
  const signed char* kbg = kp8h + (size_t)bh * SEQ * 64;
  const signed char* klg = kp8l + (size_t)bh * SEQ * 64;
  const float* skg = sk + (size_t)bh * SEQ;
  const unsigned short* vb = vt + (size_t)bh * HD * SEQ;

  float m_run[2] = {-INFINITY, -INFINITY}, l_run[2] = {0.0f, 0.0f};
  f32x4 ot[2][4];
#pragma unroll
  for (int s = 0; s < 2; ++s)
#pragma unroll
    for (int i = 0; i < 4; ++i) ot[s][i] = (f32x4)0.0f;
  const i32x4 ZERO = (i32x4){0, 0, 0, 0};

  // prologue: stage tile 0 into buf 0 (coalesced; K 4KB+4KB, V 8KB)
  {
    int u = w * 64 + lane, r = u >> 2, c = u & 3;
    gl16(kbg + r * 64 + c * 16, (char*)kbh[0] + w * 1024);
    gl16(klg + r * 64 + c * 16, (char*)kbl[0] + w * 1024);
#pragma unroll
    for (int i = 0; i < 2; ++i) {
      int u2 = (w * 2 + i) * 64 + lane, rv = u2 >> 3, cv = u2 & 7;
      gl16(vb + (size_t)rv * SEQ + cv * 8, (char*)vts[0] + (w * 2 + i) * 1024);
    }
  }

#pragma unroll 1
  for (int it = 0; it < 32; ++it) {
    const int kk0 = it * 64, cur = it & 1;
    __syncthreads();                      // buf[cur] staged; prev reads done
    // K fragments from LDS (8 x ds_read_b128, 2-way max = free)
    i32x4 kh[4], kl[4];
#pragma unroll
    for (int kt2 = 0; kt2 < 4; ++kt2) {
      int row = kt2 * 16 + li, co = (g ^ ((row >> 1) & 3)) << 4;
      kh[kt2] = *(const i32x4*)(kbh[cur] + row * 64 + co);
      kl[kt2] = *(const i32x4*)(kbl[cur] + row * 64 + co);
    }
    // stage next tile
    if (it < 31) {
      int u = w * 64 + lane, r = u >> 2, c = u & 3;
      gl16(kbg + (size_t)(kk0 + 64 + r) * 64 + c * 16, (char*)kbh[cur ^ 1] + w * 1024);
      gl16(klg + (size_t)(kk0 + 64 + r) * 64 + c * 16, (char*)kbl[cur ^ 1] + w * 1024);
#pragma unroll
      for (int i = 0; i < 2; ++i) {
        int u2 = (w * 2 + i) * 64 + lane, rv = u2 >> 3, cv = u2 & 7;
        gl16(vb + (size_t)rv * SEQ + kk0 + 64 + cv * 8, (char*)vts[cur ^ 1] + (w * 2 + i) * 1024);
      }
    }
    // QK^T: per kt2 per set, 3 int8 MFMAs (hh, mid x2) -> float scores
    f32x4 sa[2][4];
#pragma unroll
    for (int kt2 = 0; kt2 < 4; ++kt2) {
      float4 sk4 = *(const float4*)(skg + kk0 + kt2 * 16 + g * 4);
#pragma unroll
      for (int s = 0; s < 2; ++s) {
        __builtin_amdgcn_s_setprio(1);
        i32x4 hh = __builtin_amdgcn_mfma_i32_16x16x64_i8(kh[kt2], qh8[s], ZERO, 0, 0, 0);
        i32x4 mm = __builtin_amdgcn_mfma_i32_16x16x64_i8(kl[kt2], qh8[s], ZERO, 0, 0, 0);
        mm = __builtin_amdgcn_mfma_i32_16x16x64_i8(kh[kt2], ql8[s], mm, 0, 0, 0);
        __builtin_amdgcn_s_setprio(0);
        sa[s][kt2][0] = (float)((hh[0] << 8) + mm[0]) * (sq256[s] * sk4.x);
        sa[s][kt2][1] = (float)((hh[1] << 8) + mm[1]) * (sq256[s] * sk4.y);
        sa[s][kt2][2] = (float)((hh[2] << 8) + mm[2]) * (sq256[s] * sk4.z);
        sa[s][kt2][3] = (float)((hh[3] << 8) + mm[3]) * (sq256[s] * sk4.w);
      }
    }
    // online softmax (exp2 domain), per set
#pragma unroll
    for (int s = 0; s < 2; ++s) {
      float sm = -INFINITY;
#pragma unroll
      for (int kt2 = 0; kt2 < 4; ++kt2)
#pragma unroll
        for (int r = 0; r < 4; ++r) sm = fmaxf(sm, sa[s][kt2][r]);
      sm = fmaxf(sm, __shfl_xor(sm, 16));
      sm = fmaxf(sm, __shfl_xor(sm, 32));
      if (__any(sm > m_run[s] + 11.0f)) {            // defer-max: P bounded by 2^11
        float mn = fmaxf(m_run[s], sm);
        float alpha = exp2a(m_run[s] - mn);
        l_run[s] *= alpha;
#pragma unroll
        for (int i = 0; i < 4; ++i) ot[s][i] *= alpha;
        m_run[s] = mn;
      }
      float ts = 0.0f;
#pragma unroll
      for (int kt2 = 0; kt2 < 4; ++kt2)
#pragma unroll
        for (int r = 0; r < 4; ++r) {
          float e = exp2a(sa[s][kt2][r] - m_run[s]);
          sa[s][kt2][r] = e; ts += e;
        }
      ts += __shfl_xor(ts, 16);
      ts += __shfl_xor(ts, 32);
      l_run[s] += ts;
      // P^T -> per-wave LDS: kk = kt2*16 + g*4 + r at row q=li
#pragma unroll
      for (int kt2 = 0; kt2 < 4; ++kt2) {
        bf4 pk = { (__bf16)sa[s][kt2][0], (__bf16)sa[s][kt2][1],
                   (__bf16)sa[s][kt2][2], (__bf16)sa[s][kt2][3] };
        int lchunk = (kt2 << 1) | (g >> 1);
        *(bf4*)((char*)ps[w][s] + li * 128 + ((lchunk ^ (li & 7)) << 4) + ((g & 1) << 3)) = pk;
      }
    }
    asm volatile("s_waitcnt lgkmcnt(0)" ::: "memory");
    __builtin_amdgcn_sched_barrier(0);
    // PV: O^T += V^T . P^T
    bh8 pf[2][2];
#pragma unroll
    for (int s = 0; s < 2; ++s)
#pragma unroll
      for (int kc2 = 0; kc2 < 2; ++kc2)
        pf[s][kc2] = *(const bh8*)((const char*)ps[w][s] + li * 128 + ((((kc2 << 2) | g) ^ (li & 7)) << 4));
#pragma unroll
    for (int kc2 = 0; kc2 < 2; ++kc2) {
      __builtin_amdgcn_s_setprio(1);
#pragma unroll
      for (int dt = 0; dt < 4; ++dt) {
        int rowd = dt * 16 + li;
        bh8 vf = *(const bh8*)((const char*)vts[cur] + rowd * 128 + ((((kc2 << 2) | g) ^ (rowd & 7)) << 4));
        ot[0][dt] = __builtin_amdgcn_mfma_f32_16x16x32_bf16(vf, pf[0][kc2], ot[0][dt], 0, 0, 0);
        ot[1][dt] = __builtin_amdgcn_mfma_f32_16x16x32_bf16(vf, pf[1][kc2], ot[1][dt], 0, 0, 0);
      }
      __builtin_amdgcn_s_setprio(0);
    }
  }

#pragma unroll
  for (int s = 0; s < 2; ++s) {
    const float inv = 1.0f / l_run[s];
    const int n = b * SEQ + (s ? qB : qA);
#pragma unroll
    for (int dt = 0; dt < 4; ++dt) {
      float4 o4;
      o4.x = ot[s][dt][0] * inv; o4.y = ot[s][dt][1] * inv;
      o4.z = ot[s][dt][2] * inv; o4.w = ot[s][dt][3] * inv;
      *(float4*)(attn + (size_t)n * D_MODEL + h * HD + dt * 16 + g * 4) = o4;
    }
  }
}

// ---------------------------------------------------------------------------
// Per-token dynamic int8 quantization; writes packed pre-swizzled int8 rows.
// ---------------------------------------------------------------------------
__launch_bounds__(256)
__global__ void quant_k(const float* __restrict__ attn, unsigned* __restrict__ oqp,
                        float* __restrict__ osc)
{
  const int row = blockIdx.x, t = threadIdx.x;
  float4 v = *(const float4*)(attn + (size_t)row * D_MODEL + t * 4);
  float mx = fmaxf(fmaxf(fabsf(v.x), fabsf(v.y)), fmaxf(fabsf(v.z), fabsf(v.w)));
#pragma unroll
  for (int off = 1; off < 64; off <<= 1) mx = fmaxf(mx, __shfl_xor(mx, off));
  __shared__ float red[4];
  if ((t & 63) == 0) red[t >> 6] = mx;
  __syncthreads();
  mx = fmaxf(fmaxf(red[0], red[1]), fmaxf(red[2], red[3]));
  const float s = mx / 127.0f;
  if (t == 0) osc[row] = s;
  int q0 = (int)fminf(fmaxf(rintf(v.x / s), -127.f), 127.f);
  int q1 = (int)fminf(fmaxf(rintf(v.y / s), -127.f), 127.f);
  int q2 = (int)fminf(fmaxf(rintf(v.z / s), -127.f), 127.f);
  int q3 = (int)fminf(fmaxf(rintf(v.w / s), -127.f), 127.f);
  unsigned pk = ((unsigned)q0 & 255u) | (((unsigned)q1 & 255u) << 8) |
                (((unsigned)q2 & 255u) << 16) | (((unsigned)q3 & 255u) << 24);
  int kg = t >> 4, c = (t >> 2) & 3, b4 = t & 3, sw = (row >> 1) & 3;
  oqp[(size_t)row * 256 + kg * 16 + ((c ^ sw) << 2) + b4] = pk;
}

// ---------------------------------------------------------------------------
extern "C" void kernel_launch(void* const* d_in, const int* in_sizes, int n_in,
                              void* d_out, int out_size, void* d_ws, size_t ws_size,
                              hipStream_t stream)
{
  const int*   x   = (const int*)d_in[0];
  const float* xs  = (const float*)d_in[1];
  const int*   wq  = (const int*)d_in[2];
  const float* wqs = (const float*)d_in[3];
  const float* bq  = (const float*)d_in[4];
  const int*   wk  = (const int*)d_in[5];
  const float* wks = (const float*)d_in[6];
  const float* bk  = (const float*)d_in[7];
  const int*   wv  = (const int*)d_in[8];
  const float* wvs = (const float*)d_in[9];
  const float* bv  = (const float*)d_in[10];
  const int*   wo  = (const int*)d_in[11];
  const float* wos = (const float*)d_in[12];
  const float* bo  = (const float*)d_in[13];
  float* out = (float*)d_out;

  char* ws = (char*)d_ws;
  const size_t MB = 1024 * 1024;
  unsigned* xp  = (unsigned*)(ws);                     // 4 MB packed x
  unsigned* wqp = (unsigned*)(ws + 4 * MB);            // 1 MB each packed weights
  unsigned* wkp = (unsigned*)(ws + 5 * MB);
  unsigned* wvp = (unsigned*)(ws + 6 * MB);
  unsigned* wop = (unsigned*)(ws + 7 * MB);
  signed char* qp8h = (signed char*)(ws + 8 * MB);     // 4 MB each int8 q/k
  signed char* qp8l = (signed char*)(ws + 12 * MB);
  signed char* kp8h = (signed char*)(ws + 16 * MB);
  signed char* kp8l = (signed char*)(ws + 20 * MB);
  float*       sqs  = (float*)(ws + 24 * MB);          // 256 KB
  float*       sks  = (float*)(ws + 24 * MB + 256 * 1024);
  unsigned short* vtw = (unsigned short*)(ws + 25 * MB);  // 8 MB
  float*          att = (float*)(ws + 33 * MB);           // 16 MB
  unsigned*       oqp = (unsigned*)(ws);                  // overlay on xp (dead)
  float*          osc = (float*)(ws + 4 * MB);            // overlay on wqp (dead)

  const float SC = 0.125f * 1.44269504088896340736f;   // (1/sqrt(hd)) * log2(e)
  dim3 blk(256);
  pack_k<<<dim3(8192), blk, 0, stream>>>(x, wq, wk, wv, wo, xp, wqp, wkp, wvp, wop);
  gemmQKV_k<<<dim3(1536), blk, 0, stream>>>((const signed char*)xp, (const signed char*)wqp,
                                            (const signed char*)wkp, (const signed char*)wvp,
                                            xs, wqs, bq, wks, bk, wvs, bv, SC,
                                            qp8h, qp8l, kp8h, kp8l, sqs, sks, vtw);
  attn_k<<<dim3(16, NH, 2), blk, 0, stream>>>(qp8h, qp8l, kp8h, kp8l, sqs, sks, vtw, att);
  quant_k<<<dim3(4096), blk, 0, stream>>>(att, oqp, osc);
  gemmO_k<<<dim3(512), blk, 0, stream>>>((const signed char*)oqp, (const signed char*)wop,
                                         osc, wos, bo, out);
}